// Round 11
// baseline (966.069 us; speedup 1.0000x reference)
//
#include <hip/hip_runtime.h>
#include <hip/hip_bf16.h>
#include <math.h>

constexpr int Bx = 4, Lx = 1024, DM = 512, DS = 16, NL = 4, EDx = 1024;
constexpr int DTR = 32;

typedef __attribute__((ext_vector_type(8))) short short8v;   // 8 bf16 = 4 VGPR
typedef __attribute__((ext_vector_type(4))) short short4v;
typedef __attribute__((ext_vector_type(4))) float f32x4;

__device__ inline short f2bf(float f) {
  union { __hip_bfloat16 h; short s; } u;
  u.h = __float2bfloat16(f);
  return u.s;
}
__device__ inline float bf2f(short s) {
  union { __hip_bfloat16 h; short s; } u;
  u.s = s;
  return __bfloat162float(u.h);
}
__device__ inline void store8(short* p, short8v v) {   // 8B-aligned LDS store
  *(short4v*)(p)     = __builtin_shufflevector(v, v, 0, 1, 2, 3);
  *(short4v*)(p + 4) = __builtin_shufflevector(v, v, 4, 5, 6, 7);
}

// ---------------- x = seq @ Wi^T + bi ----------------
__global__ __launch_bounds__(256) void k_init_x(const float* __restrict__ seq,
    const float* __restrict__ Wi, const float* __restrict__ bi, float* __restrict__ x) {
  int idx = blockIdx.x * 256 + threadIdx.x;      // over B*L*DM
  int d = idx & (DM - 1);
  int bl = idx >> 9;
  float s0 = seq[bl * 3 + 0], s1 = seq[bl * 3 + 1], s2 = seq[bl * 3 + 2];
  x[idx] = bi[d] + s0 * Wi[d * 3 + 0] + s1 * Wi[d * 3 + 1] + s2 * Wi[d * 3 + 2];
}

// ---------------- fp32 -> bf16 hi/lo split (elementwise, BW-bound) ----------------
__global__ __launch_bounds__(256) void k_split(const float* __restrict__ s,
    short* __restrict__ hi, short* __restrict__ lo) {
  int i = blockIdx.x * 256 + threadIdx.x;        // over n/4
  const float4 v = ((const float4*)s)[i];
  short4v h, l;
  h.x = f2bf(v.x); l.x = f2bf(v.x - bf2f(h.x));
  h.y = f2bf(v.y); l.y = f2bf(v.y - bf2f(h.y));
  h.z = f2bf(v.z); l.z = f2bf(v.z - bf2f(h.z));
  h.w = f2bf(v.w); l.w = f2bf(v.w - bf2f(h.w));
  ((short4v*)hi)[i] = h;
  ((short4v*)lo)[i] = l;
}

// ============ bf16-pair MFMA GEMM: C[M,N] = (Ah+Al)[M,K] @ (Bh+Bl)[N,K]^T ============
// Pre-split operands; 4 waves 2x2; 16x16x32 bf16 MFMA; 3-term split-fp32 product.
template <int BM, int BN>
__global__ __launch_bounds__(256) void k_gemm_bfp(
    const short* __restrict__ Ahg, const short* __restrict__ Alg,
    const short* __restrict__ Bhg, const short* __restrict__ Blg,
    float* __restrict__ C, int ldc, int K) {
  constexpr int MR = BM / 32, NR = BN / 32;
  __shared__ short Ah[BM][44], Al[BM][44], Bh[BN][44], Bl[BN][44];
  const int tid = threadIdx.x;
  const int w = tid >> 6, lane = tid & 63;
  const int wr = w >> 1, wc = w & 1;
  const int r16 = lane & 15, kh = lane >> 4;
  const int m0 = blockIdx.x * BM, n0 = blockIdx.y * BN;

  f32x4 acc[MR][NR];
  #pragma unroll
  for (int i = 0; i < MR; ++i)
    #pragma unroll
    for (int j = 0; j < NR; ++j) {
      acc[i][j][0] = 0.f; acc[i][j][1] = 0.f; acc[i][j][2] = 0.f; acc[i][j][3] = 0.f;
    }

  for (int k0 = 0; k0 < K; k0 += 32) {
    __syncthreads();
    #pragma unroll
    for (int p = 0; p < BM / 64; ++p) {
      int f = tid + p * 256;                 // BM*4 short8s per operand
      int r = f >> 2, c8 = (f & 3) << 3;
      size_t g = (size_t)(m0 + r) * K + k0 + c8;
      store8(&Ah[r][c8], *(const short8v*)(Ahg + g));
      store8(&Al[r][c8], *(const short8v*)(Alg + g));
    }
    #pragma unroll
    for (int p = 0; p < BN / 64; ++p) {
      int f = tid + p * 256;
      int r = f >> 2, c8 = (f & 3) << 3;
      size_t g = (size_t)(n0 + r) * K + k0 + c8;
      store8(&Bh[r][c8], *(const short8v*)(Bhg + g));
      store8(&Bl[r][c8], *(const short8v*)(Blg + g));
    }
    __syncthreads();
    short8v ah[MR], al[MR], bh[NR], bl[NR];
    #pragma unroll
    for (int i = 0; i < MR; ++i) {
      int rr = wr * (BM / 2) + i * 16 + r16;
      ah[i] = *(const short8v*)(&Ah[rr][kh * 8]);
      al[i] = *(const short8v*)(&Al[rr][kh * 8]);
    }
    #pragma unroll
    for (int j = 0; j < NR; ++j) {
      int cc = wc * (BN / 2) + j * 16 + r16;
      bh[j] = *(const short8v*)(&Bh[cc][kh * 8]);
      bl[j] = *(const short8v*)(&Bl[cc][kh * 8]);
    }
    #pragma unroll
    for (int i = 0; i < MR; ++i)
      #pragma unroll
      for (int j = 0; j < NR; ++j) {
        acc[i][j] = __builtin_amdgcn_mfma_f32_16x16x32_bf16(ah[i], bh[j], acc[i][j], 0, 0, 0);
        acc[i][j] = __builtin_amdgcn_mfma_f32_16x16x32_bf16(ah[i], bl[j], acc[i][j], 0, 0, 0);
        acc[i][j] = __builtin_amdgcn_mfma_f32_16x16x32_bf16(al[i], bh[j], acc[i][j], 0, 0, 0);
      }
  }
  #pragma unroll
  for (int i = 0; i < MR; ++i) {
    int row_base = m0 + wr * (BM / 2) + i * 16 + kh * 4;   // D: col=lane&15, row=(lane>>4)*4+reg
    #pragma unroll
    for (int j = 0; j < NR; ++j) {
      int col = n0 + wc * (BN / 2) + j * 16 + r16;
      #pragma unroll
      for (int r = 0; r < 4; ++r)
        C[(size_t)(row_base + r) * ldc + col] = acc[i][j][r];
    }
  }
}

// ============ x_proj split-K bf16x3 MFMA (fp32 input, in-kernel split) ============
template <int SK>
__global__ __launch_bounds__(256) void k_xproj_mfma(
    const float* __restrict__ A,      // XB [4096][1024]
    const float* __restrict__ W,      // Wx [64][1024]
    float* __restrict__ PART) {       // [SK][4096][64]
  constexpr int BM = 128, BN = 64, KS = 1024 / SK;
  constexpr int MR = 4, NR = 2;       // wave tile 64x32
  __shared__ short Ah[BM][44], Al[BM][44], Bh[BN][44], Bl[BN][44];
  const int tid = threadIdx.x;
  const int w = tid >> 6, lane = tid & 63;
  const int wr = w >> 1, wc = w & 1;
  const int r16 = lane & 15, kh = lane >> 4;
  const int m0 = blockIdx.x * BM;
  const int kbeg = blockIdx.z * KS;

  f32x4 acc[MR][NR];
  #pragma unroll
  for (int i = 0; i < MR; ++i)
    #pragma unroll
    for (int j = 0; j < NR; ++j) {
      acc[i][j][0] = 0.f; acc[i][j][1] = 0.f; acc[i][j][2] = 0.f; acc[i][j][3] = 0.f;
    }

  for (int k0 = kbeg; k0 < kbeg + KS; k0 += 32) {
    __syncthreads();
    #pragma unroll
    for (int p = 0; p < BM / 32; ++p) {
      int f = tid + p * 256;
      int r = f >> 3, c = (f & 7) << 2;
      const float4 v = *(const float4*)(A + (size_t)(m0 + r) * 1024 + k0 + c);
      short h0 = f2bf(v.x), h1 = f2bf(v.y), h2 = f2bf(v.z), h3 = f2bf(v.w);
      Ah[r][c + 0] = h0; Ah[r][c + 1] = h1; Ah[r][c + 2] = h2; Ah[r][c + 3] = h3;
      Al[r][c + 0] = f2bf(v.x - bf2f(h0));
      Al[r][c + 1] = f2bf(v.y - bf2f(h1));
      Al[r][c + 2] = f2bf(v.z - bf2f(h2));
      Al[r][c + 3] = f2bf(v.w - bf2f(h3));
    }
    #pragma unroll
    for (int p = 0; p < BN / 32; ++p) {
      int f = tid + p * 256;
      int r = f >> 3, c = (f & 7) << 2;
      const float4 v = *(const float4*)(W + (size_t)r * 1024 + k0 + c);
      short h0 = f2bf(v.x), h1 = f2bf(v.y), h2 = f2bf(v.z), h3 = f2bf(v.w);
      Bh[r][c + 0] = h0; Bh[r][c + 1] = h1; Bh[r][c + 2] = h2; Bh[r][c + 3] = h3;
      Bl[r][c + 0] = f2bf(v.x - bf2f(h0));
      Bl[r][c + 1] = f2bf(v.y - bf2f(h1));
      Bl[r][c + 2] = f2bf(v.z - bf2f(h2));
      Bl[r][c + 3] = f2bf(v.w - bf2f(h3));
    }
    __syncthreads();
    short8v ah[MR], al[MR], bh[NR], bl[NR];
    #pragma unroll
    for (int i = 0; i < MR; ++i) {
      int rr = wr * 64 + i * 16 + r16;
      ah[i] = *(const short8v*)(&Ah[rr][kh * 8]);
      al[i] = *(const short8v*)(&Al[rr][kh * 8]);
    }
    #pragma unroll
    for (int j = 0; j < NR; ++j) {
      int cc = wc * 32 + j * 16 + r16;
      bh[j] = *(const short8v*)(&Bh[cc][kh * 8]);
      bl[j] = *(const short8v*)(&Bl[cc][kh * 8]);
    }
    #pragma unroll
    for (int i = 0; i < MR; ++i)
      #pragma unroll
      for (int j = 0; j < NR; ++j) {
        acc[i][j] = __builtin_amdgcn_mfma_f32_16x16x32_bf16(ah[i], bh[j], acc[i][j], 0, 0, 0);
        acc[i][j] = __builtin_amdgcn_mfma_f32_16x16x32_bf16(ah[i], bl[j], acc[i][j], 0, 0, 0);
        acc[i][j] = __builtin_amdgcn_mfma_f32_16x16x32_bf16(al[i], bh[j], acc[i][j], 0, 0, 0);
      }
  }
  float* Cp = PART + (size_t)blockIdx.z * (4096 * 64);
  #pragma unroll
  for (int i = 0; i < MR; ++i) {
    int row_base = m0 + wr * 64 + i * 16 + kh * 4;
    #pragma unroll
    for (int j = 0; j < NR; ++j) {
      int col = wc * 32 + j * 16 + r16;
      #pragma unroll
      for (int r = 0; r < 4; ++r)
        Cp[(size_t)(row_base + r) * 64 + col] = acc[i][j][r];
    }
  }
}

template <int SK>
__global__ __launch_bounds__(256) void k_redux(const float* __restrict__ PART,
                                               float* __restrict__ out) {
  int i = blockIdx.x * 256 + threadIdx.x;      // over 4096*64/4 float4s
  float4 s = ((const float4*)PART)[i];
  #pragma unroll
  for (int k = 1; k < SK; ++k) {
    const float4 v = ((const float4*)PART)[i + k * 65536];
    s.x += v.x; s.y += v.y; s.z += v.z; s.w += v.w;
  }
  ((float4*)out)[i] = s;
}

// ---------------- generic fp32 GEMM (kept for dt_proj) ----------------
template <int BM, int BN, int EPI>
__global__ __launch_bounds__(256) void k_gemm_tn(
    const float* __restrict__ A, int lda,
    const float* __restrict__ W, int ldw,
    const float* __restrict__ bias,
    float* __restrict__ C, int ldc, int K) {
  constexpr int BK = 16;
  constexpr int MR = BM / 16, NR = BN / 16;
  __shared__ float As[BK][BM + 4];
  __shared__ float Bs[BK][BN + 4];
  const int tid = threadIdx.x;
  const int tx = tid & 15, ty = tid >> 4;
  const int m0 = blockIdx.x * BM, n0 = blockIdx.y * BN;
  const int arow = tid >> 2;
  const int akol = (tid & 3) << 2;
  float acc[MR][NR] = {};
  for (int k0 = 0; k0 < K; k0 += BK) {
    #pragma unroll
    for (int r = 0; r < BM / 64; ++r) {
      int m = arow + r * 64;
      const float4 v = *(const float4*)(A + (size_t)(m0 + m) * lda + k0 + akol);
      As[akol + 0][m] = v.x; As[akol + 1][m] = v.y;
      As[akol + 2][m] = v.z; As[akol + 3][m] = v.w;
    }
    if constexpr (BN >= 64) {
      #pragma unroll
      for (int r = 0; r < BN / 64; ++r) {
        int n = arow + r * 64;
        const float4 v = *(const float4*)(W + (size_t)(n0 + n) * ldw + k0 + akol);
        Bs[akol + 0][n] = v.x; Bs[akol + 1][n] = v.y;
        Bs[akol + 2][n] = v.z; Bs[akol + 3][n] = v.w;
      }
    } else {
      if (arow < BN) {
        const float4 v = *(const float4*)(W + (size_t)(n0 + arow) * ldw + k0 + akol);
        Bs[akol + 0][arow] = v.x; Bs[akol + 1][arow] = v.y;
        Bs[akol + 2][arow] = v.z; Bs[akol + 3][arow] = v.w;
      }
    }
    __syncthreads();
    #pragma unroll
    for (int k = 0; k < BK; ++k) {
      float af[MR], bf[NR];
      #pragma unroll
      for (int i = 0; i < MR; ++i) af[i] = As[k][ty * MR + i];
      #pragma unroll
      for (int j = 0; j < NR; ++j) bf[j] = Bs[k][tx * NR + j];
      #pragma unroll
      for (int i = 0; i < MR; ++i)
        #pragma unroll
        for (int j = 0; j < NR; ++j)
          acc[i][j] = fmaf(af[i], bf[j], acc[i][j]);
    }
    __syncthreads();
  }
  #pragma unroll
  for (int i = 0; i < MR; ++i) {
    int m = m0 + ty * MR + i;
    #pragma unroll
    for (int j = 0; j < NR; ++j) {
      int n = n0 + tx * NR + j;
      float v = acc[i][j];
      if constexpr (EPI == 1) {
        v += bias[n];
        v = (v > 20.f) ? v : log1pf(__expf(v));
      }
      C[(size_t)m * ldc + n] = v;
    }
  }
}

// ---------------- causal depthwise conv (D_CONV=4) + bias + silu, x4 vectorized ----------------
__global__ __launch_bounds__(256) void k_conv_silu4(const float* __restrict__ xz,
    const float* __restrict__ cw, const float* __restrict__ cb, float* __restrict__ xb) {
  int idx = blockIdx.x * 256 + threadIdx.x;    // over B*L*ED/4
  int e4 = (idx & 255) << 2;                   // e base
  int bl = idx >> 8;
  int l = bl & (Lx - 1);
  const float4 w0 = ((const float4*)cw)[e4 + 0];
  const float4 w1 = ((const float4*)cw)[e4 + 1];
  const float4 w2 = ((const float4*)cw)[e4 + 2];
  const float4 w3 = ((const float4*)cw)[e4 + 3];
  float4 acc = ((const float4*)cb)[idx & 255];
  const float* base = xz + (size_t)bl * (2 * EDx) + e4;
  if (l >= 3) { const float4 x = *(const float4*)(base - 3 * 2 * EDx);
    acc.x = fmaf(x.x, w0.x, acc.x); acc.y = fmaf(x.y, w1.x, acc.y);
    acc.z = fmaf(x.z, w2.x, acc.z); acc.w = fmaf(x.w, w3.x, acc.w); }
  if (l >= 2) { const float4 x = *(const float4*)(base - 2 * 2 * EDx);
    acc.x = fmaf(x.x, w0.y, acc.x); acc.y = fmaf(x.y, w1.y, acc.y);
    acc.z = fmaf(x.z, w2.y, acc.z); acc.w = fmaf(x.w, w3.y, acc.w); }
  if (l >= 1) { const float4 x = *(const float4*)(base - 1 * 2 * EDx);
    acc.x = fmaf(x.x, w0.z, acc.x); acc.y = fmaf(x.y, w1.z, acc.y);
    acc.z = fmaf(x.z, w2.z, acc.z); acc.w = fmaf(x.w, w3.z, acc.w); }
  { const float4 x = *(const float4*)(base);
    acc.x = fmaf(x.x, w0.w, acc.x); acc.y = fmaf(x.y, w1.w, acc.y);
    acc.z = fmaf(x.z, w2.w, acc.z); acc.w = fmaf(x.w, w3.w, acc.w); }
  acc.x /= (1.f + __expf(-acc.x));
  acc.y /= (1.f + __expf(-acc.y));
  acc.z /= (1.f + __expf(-acc.z));
  acc.w /= (1.f + __expf(-acc.w));
  ((float4*)xb)[idx] = acc;
}

// ==================== chunked selective scan (templated on chunk count) ====================
#define CVT4(V) { V.x = -__expf(V.x) * 1.44269504f; V.y = -__expf(V.y) * 1.44269504f; \
                  V.z = -__expf(V.z) * 1.44269504f; V.w = -__expf(V.w) * 1.44269504f; }

#define ST4PQ(Av, Pv, Qv, Bv) { \
  float a0 = exp2f(dl * Av.x); Pv.x *= a0; Qv.x = fmaf(a0, Qv.x, dx * Bv.x); \
  float a1 = exp2f(dl * Av.y); Pv.y *= a1; Qv.y = fmaf(a1, Qv.y, dx * Bv.y); \
  float a2 = exp2f(dl * Av.z); Pv.z *= a2; Qv.z = fmaf(a2, Qv.z, dx * Bv.z); \
  float a3 = exp2f(dl * Av.w); Pv.w *= a3; Qv.w = fmaf(a3, Qv.w, dx * Bv.w); }

#define ST4Y(Av, Hv, Bv, Cv) { \
  float a0 = exp2f(dl * Av.x); Hv.x = fmaf(a0, Hv.x, dx * Bv.x); y = fmaf(Hv.x, Cv.x, y); \
  float a1 = exp2f(dl * Av.y); Hv.y = fmaf(a1, Hv.y, dx * Bv.y); y = fmaf(Hv.y, Cv.y, y); \
  float a2 = exp2f(dl * Av.z); Hv.z = fmaf(a2, Hv.z, dx * Bv.z); y = fmaf(Hv.z, Cv.z, y); \
  float a3 = exp2f(dl * Av.w); Hv.w = fmaf(a3, Hv.w, dx * Bv.w); y = fmaf(Hv.w, Cv.w, y); }

template <int NCt>
__global__ __launch_bounds__(256) void k_scan1(
    const float* __restrict__ del, const float* __restrict__ xb,
    const float* __restrict__ dbc, const float* __restrict__ Alog,
    float* __restrict__ PQ) {
  constexpr int CTt = Lx / NCt;
  const int idx = blockIdx.x * 256 + threadIdx.x;   // c*4096 + ch
  const int ch = idx & 4095, c = idx >> 12;
  const int b = ch >> 10, e = ch & 1023;
  float4 A0, A1, A2, A3;
  {
    const float4* ar = (const float4*)(Alog + e * DS);
    A0 = ar[0]; A1 = ar[1]; A2 = ar[2]; A3 = ar[3];
    CVT4(A0); CVT4(A1); CVT4(A2); CVT4(A3);
  }
  float4 P0 = {1,1,1,1}, P1 = {1,1,1,1}, P2 = {1,1,1,1}, P3 = {1,1,1,1};
  float4 Q0 = {0,0,0,0}, Q1 = {0,0,0,0}, Q2 = {0,0,0,0}, Q3 = {0,0,0,0};
  const size_t bl0 = (size_t)b * Lx + c * CTt;
  const float* dp  = del + bl0 * EDx + e;
  const float* xp  = xb  + bl0 * EDx + e;
  const float* bcp = dbc + bl0 * 64 + 32;
  #pragma unroll 2
  for (int i = 0; i < CTt; ++i) {
    float dl = dp[0];
    float xbl = xp[0];
    float dx = dl * xbl;
    const float4* bp = (const float4*)bcp;
    float4 B0 = bp[0], B1 = bp[1], B2 = bp[2], B3 = bp[3];
    ST4PQ(A0, P0, Q0, B0); ST4PQ(A1, P1, Q1, B1);
    ST4PQ(A2, P2, Q2, B2); ST4PQ(A3, P3, Q3, B3);
    dp += EDx; xp += EDx; bcp += 64;
  }
  float4* o = (float4*)(PQ + (size_t)idx * 32);
  o[0] = P0; o[1] = P1; o[2] = P2; o[3] = P3;
  o[4] = Q0; o[5] = Q1; o[6] = Q2; o[7] = Q3;
}

// Pass 2: sequential combine over chunks, 8-deep two-bank software pipeline.
template <int NCt>
__global__ __launch_bounds__(256) void k_scan2(float* __restrict__ PQ) {
  const int idx = blockIdx.x * 256 + threadIdx.x;   // ch*16 + n
  const int ch = idx >> 4, n = idx & 15;
  constexpr int G = 8;
  const size_t off = (size_t)ch * 32 + n;
  float Pa[G], Qa[G], Pb[G], Qb[G];
  #pragma unroll
  for (int j = 0; j < G; ++j) {
    size_t base = (size_t)j * (4096 * 32) + off;
    Pa[j] = PQ[base]; Qa[j] = PQ[base + 16];
  }
  float H = 0.f;
  #pragma unroll
  for (int gp = 0; gp < NCt / (2 * G); ++gp) {
    const int cA = 2 * gp * G, cB = (2 * gp + 1) * G, cN = (2 * gp + 2) * G;
    #pragma unroll
    for (int j = 0; j < G; ++j) {
      size_t base = (size_t)(cB + j) * (4096 * 32) + off;
      Pb[j] = PQ[base]; Qb[j] = PQ[base + 16];
    }
    #pragma unroll
    for (int j = 0; j < G; ++j) {
      size_t base = (size_t)(cA + j) * (4096 * 32) + off;
      PQ[base + 16] = H;                  // carry-in for chunk cA+j
      H = fmaf(Pa[j], H, Qa[j]);
    }
    if (gp + 1 < NCt / (2 * G)) {
      #pragma unroll
      for (int j = 0; j < G; ++j) {
        size_t base = (size_t)(cN + j) * (4096 * 32) + off;
        Pa[j] = PQ[base]; Qa[j] = PQ[base + 16];
      }
    }
    #pragma unroll
    for (int j = 0; j < G; ++j) {
      size_t base = (size_t)(cB + j) * (4096 * 32) + off;
      PQ[base + 16] = H;
      H = fmaf(Pb[j], H, Qb[j]);
    }
  }
}

template <int NCt>
__global__ __launch_bounds__(256) void k_scan3(
    float* __restrict__ dy,               // in: delta, out: y (in place)
    const float* __restrict__ xb,
    const float* __restrict__ dbc,
    const float* __restrict__ xz,         // z at column offset ED
    const float* __restrict__ Alog, const float* __restrict__ Dp,
    const float* __restrict__ PQ) {
  constexpr int CTt = Lx / NCt;
  const int idx = blockIdx.x * 256 + threadIdx.x;   // c*4096 + ch
  const int ch = idx & 4095, c = idx >> 12;
  const int b = ch >> 10, e = ch & 1023;
  float4 A0, A1, A2, A3;
  {
    const float4* ar = (const float4*)(Alog + e * DS);
    A0 = ar[0]; A1 = ar[1]; A2 = ar[2]; A3 = ar[3];
    CVT4(A0); CVT4(A1); CVT4(A2); CVT4(A3);
  }
  float4 H0, H1, H2, H3;
  {
    const float4* hi = (const float4*)(PQ + (size_t)idx * 32 + 16);
    H0 = hi[0]; H1 = hi[1]; H2 = hi[2]; H3 = hi[3];
  }
  const float De = Dp[e];
  const size_t bl0 = (size_t)b * Lx + c * CTt;
  float* dyp = dy + bl0 * EDx + e;
  const float* xp  = xb + bl0 * EDx + e;
  const float* bcp = dbc + bl0 * 64 + 32;
  const float* zp  = xz + bl0 * (2 * EDx) + EDx + e;
  #pragma unroll 2
  for (int i = 0; i < CTt; ++i) {
    float dl = dyp[0];
    float xbl = xp[0];
    float zv = zp[0];
    float dx = dl * xbl;
    const float4* bp = (const float4*)bcp;
    float4 B0 = bp[0], B1 = bp[1], B2 = bp[2], B3 = bp[3];
    float4 C0 = bp[4], C1 = bp[5], C2 = bp[6], C3 = bp[7];
    float y = 0.f;
    ST4Y(A0, H0, B0, C0); ST4Y(A1, H1, B1, C1);
    ST4Y(A2, H2, B2, C2); ST4Y(A3, H3, B3, C3);
    y = fmaf(De, xbl, y);
    y *= zv / (1.f + __expf(-zv));
    dyp[0] = y;
    dyp += EDx; xp += EDx; bcp += 64; zp += 2 * EDx;
  }
}

// ---------------- last-token LayerNorm + head ----------------
__global__ __launch_bounds__(256) void k_ln_head(
    const float* __restrict__ x, const float* __restrict__ g,
    const float* __restrict__ be, const float* __restrict__ Wo,
    const float* __restrict__ bo, float* __restrict__ out) {
  const int b = blockIdx.x;
  const int t = threadIdx.x;
  const float* xr = x + ((size_t)b * Lx + (Lx - 1)) * DM;
  __shared__ float w1[4], w2[4];
  __shared__ float xn[DM];
  __shared__ float hp[20][8];
  float a0 = xr[t], a1 = xr[t + 256];
  float p = a0 + a1;
  #pragma unroll
  for (int o = 32; o > 0; o >>= 1) p += __shfl_down(p, o);
  if ((t & 63) == 0) w1[t >> 6] = p;
  __syncthreads();
  float mean = (w1[0] + w1[1] + w1[2] + w1[3]) * (1.f / DM);
  float d0 = a0 - mean, d1 = a1 - mean;
  p = d0 * d0 + d1 * d1;
  #pragma unroll
  for (int o = 32; o > 0; o >>= 1) p += __shfl_down(p, o);
  if ((t & 63) == 0) w2[t >> 6] = p;
  __syncthreads();
  float rstd = rsqrtf((w2[0] + w2[1] + w2[2] + w2[3]) * (1.f / DM) + 1e-5f);
  xn[t] = d0 * rstd * g[t] + be[t];
  xn[t + 256] = d1 * rstd * g[t + 256] + be[t + 256];
  __syncthreads();
  if (t < 160) {
    int j = t / 8, sg = t % 8;
    const float* wr = Wo + (size_t)j * DM + sg * 64;
    const float* xs = xn + sg * 64;
    float s = 0.f;
    #pragma unroll
    for (int k = 0; k < 64; ++k) s = fmaf(xs[k], wr[k], s);
    hp[j][sg] = s;
  }
  __syncthreads();
  if (t < 20) {
    float s = bo[t];
    #pragma unroll
    for (int k = 0; k < 8; ++k) s += hp[t][k];
    out[b * 20 + t] = s;
  }
}

extern "C" void kernel_launch(void* const* d_in, const int* in_sizes, int n_in,
                              void* d_out, int out_size, void* d_ws, size_t ws_size,
                              hipStream_t stream) {
  (void)in_sizes; (void)n_in; (void)out_size;
  const float* seq    = (const float*)d_in[0];
  const float* Wi     = (const float*)d_in[1];
  const float* bi     = (const float*)d_in[2];
  const float* Wo     = (const float*)d_in[3];
  const float* bo     = (const float*)d_in[4];
  const float* ln_g   = (const float*)d_in[5];
  const float* ln_b   = (const float*)d_in[6];
  const float* lWin   = (const float*)d_in[7];
  const float* lconvw = (const float*)d_in[8];
  const float* lconvb = (const float*)d_in[9];
  const float* lWx    = (const float*)d_in[10];
  const float* lWdt   = (const float*)d_in[11];
  const float* lbdt   = (const float*)d_in[12];
  const float* lAlog  = (const float*)d_in[13];
  const float* lD     = (const float*)d_in[14];
  const float* lWout  = (const float*)d_in[15];

  float* ws  = (float*)d_ws;
  float* X   = ws;                 // [4096][512]   = 2,097,152 floats
  float* XZ  = X + 2097152;        // [4096][2048]  = 8,388,608
  float* XB  = XZ + 8388608;       // [4096][1024]  = 4,194,304
  float* DBC = XB + 4194304;       // [4096][64]    = 262,144
  float* DEL = DBC + 262144;       // [4096][1024]  = 4,194,304 (delta, then y)
  float* PQ  = DEL + 4194304;      // [NC*4096][32] floats; bf16 pairs + PART alias here

  // bf16 pair buffers inside PQ (disjoint lifetimes, see per-layer timeline)
  short* PQs   = (short*)PQ;
  short* Xh    = PQs;                   // 2,097,152 shorts  (dead before PART/scan)
  short* Xl    = PQs + 2097152;
  short* Winh  = PQs + 4194304;         // 1,048,576 shorts
  short* Winl  = PQs + 5242880;
  short* Yh    = PQs;                   // 4,194,304 shorts  (written after scan3)
  short* Yl    = PQs + 4194304;
  short* Wouth = PQs + 8388608;         // 524,288 shorts
  short* Woutl = PQs + 8912896;
  float* PART  = PQ;                    // [8][4096][64] = 2M floats (xproj phase)

  // NC=128 needs 143,654,912 B; NC=64 needs 110,100,480 B (proven available r7).
  const bool nc128 = ws_size >= (size_t)143654912;

  k_init_x<<<dim3(Bx * Lx * DM / 256), 256, 0, stream>>>(seq, Wi, bi, X);

  for (int i = 0; i < NL; ++i) {
    const float* Win  = lWin   + (size_t)i * 2048 * 512;
    const float* cw   = lconvw + (size_t)i * EDx * 4;
    const float* cb   = lconvb + (size_t)i * EDx;
    const float* Wx   = lWx    + (size_t)i * 64 * EDx;
    const float* Wdt  = lWdt   + (size_t)i * EDx * DTR;
    const float* bdt  = lbdt   + (size_t)i * EDx;
    const float* Alog = lAlog  + (size_t)i * EDx * DS;
    const float* Dp   = lD     + (size_t)i * EDx;
    const float* Wout = lWout  + (size_t)i * DM * EDx;

    // split X, Win -> bf16 pairs; xz = x @ Win^T  (bf16-pair MFMA)
    k_split<<<dim3(2048), 256, 0, stream>>>(X, Xh, Xl);
    k_split<<<dim3(1024), 256, 0, stream>>>(Win, Winh, Winl);
    k_gemm_bfp<128, 128><<<dim3(32, 16), 256, 0, stream>>>(Xh, Xl, Winh, Winl, XZ, 2 * EDx, DM);
    // xb = silu(causal_dwconv(xz[:, :ED]) + cb)
    k_conv_silu4<<<dim3(Bx * Lx * EDx / 1024), 256, 0, stream>>>(XZ, cw, cb, XB);
    // dbc = xb @ Wx^T  (split-K MFMA + reduce)
    k_xproj_mfma<8><<<dim3(32, 1, 8), 256, 0, stream>>>(XB, Wx, PART);
    k_redux<8><<<dim3(256), 256, 0, stream>>>(PART, DBC);
    // delta = softplus(dbc[:, :32] @ Wdt^T + bdt)
    k_gemm_tn<128, 64, 1><<<dim3(32, 16), 256, 0, stream>>>(DBC, 64, Wdt, DTR, bdt, DEL, EDx, DTR);
    // chunked selective scan + gating, y written over DEL
    if (nc128) {
      k_scan1<128><<<dim3(4096 * 128 / 256), 256, 0, stream>>>(DEL, XB, DBC, Alog, PQ);
      k_scan2<128><<<dim3(4096 * DS / 256), 256, 0, stream>>>(PQ);
      k_scan3<128><<<dim3(4096 * 128 / 256), 256, 0, stream>>>(DEL, XB, DBC, XZ, Alog, Dp, PQ);
    } else {
      k_scan1<64><<<dim3(4096 * 64 / 256), 256, 0, stream>>>(DEL, XB, DBC, Alog, PQ);
      k_scan2<64><<<dim3(4096 * DS / 256), 256, 0, stream>>>(PQ);
      k_scan3<64><<<dim3(4096 * 64 / 256), 256, 0, stream>>>(DEL, XB, DBC, XZ, Alog, Dp, PQ);
    }
    // split y, Wout -> pairs; x = y @ Wout^T  (bf16-pair MFMA)
    k_split<<<dim3(4096), 256, 0, stream>>>(DEL, Yh, Yl);
    k_split<<<dim3(512), 256, 0, stream>>>(Wout, Wouth, Woutl);
    k_gemm_bfp<128, 64><<<dim3(32, 8), 256, 0, stream>>>(Yh, Yl, Wouth, Woutl, X, DM, EDx);
  }

  k_ln_head<<<dim3(Bx), 256, 0, stream>>>(X, ln_g, ln_b, Wo, bo, (float*)d_out);
}

// Round 12
// 945.111 us; speedup vs baseline: 1.0222x; 1.0222x over previous
//
#include <hip/hip_runtime.h>
#include <hip/hip_bf16.h>
#include <math.h>

constexpr int Bx = 4, Lx = 1024, DM = 512, DS = 16, NL = 4, EDx = 1024;
constexpr int DTR = 32;

typedef __attribute__((ext_vector_type(8))) short short8v;   // 8 bf16 = 4 VGPR
typedef __attribute__((ext_vector_type(4))) short short4v;
typedef __attribute__((ext_vector_type(4))) float f32x4;

__device__ inline short f2bf(float f) {
  union { __hip_bfloat16 h; short s; } u;
  u.h = __float2bfloat16(f);
  return u.s;
}
__device__ inline float bf2f(short s) {
  union { __hip_bfloat16 h; short s; } u;
  u.s = s;
  return __bfloat162float(u.h);
}
__device__ inline void store8(short* p, short8v v) {   // 8B-aligned LDS store
  *(short4v*)(p)     = __builtin_shufflevector(v, v, 0, 1, 2, 3);
  *(short4v*)(p + 4) = __builtin_shufflevector(v, v, 4, 5, 6, 7);
}

// ---------------- x = seq @ Wi^T + bi  (+ bf16 hi/lo pairs fused) ----------------
__global__ __launch_bounds__(256) void k_init_x(const float* __restrict__ seq,
    const float* __restrict__ Wi, const float* __restrict__ bi,
    float* __restrict__ x, short* __restrict__ xh, short* __restrict__ xl) {
  int idx = blockIdx.x * 256 + threadIdx.x;      // over B*L*DM
  int d = idx & (DM - 1);
  int bl = idx >> 9;
  float s0 = seq[bl * 3 + 0], s1 = seq[bl * 3 + 1], s2 = seq[bl * 3 + 2];
  float v = bi[d] + s0 * Wi[d * 3 + 0] + s1 * Wi[d * 3 + 1] + s2 * Wi[d * 3 + 2];
  x[idx] = v;
  short h = f2bf(v);
  xh[idx] = h;
  xl[idx] = f2bf(v - bf2f(h));
}

// ---------------- fp32 -> bf16 hi/lo split (weights only now) ----------------
__global__ __launch_bounds__(256) void k_split(const float* __restrict__ s,
    short* __restrict__ hi, short* __restrict__ lo) {
  int i = blockIdx.x * 256 + threadIdx.x;        // over n/4
  const float4 v = ((const float4*)s)[i];
  short4v h, l;
  h.x = f2bf(v.x); l.x = f2bf(v.x - bf2f(h.x));
  h.y = f2bf(v.y); l.y = f2bf(v.y - bf2f(h.y));
  h.z = f2bf(v.z); l.z = f2bf(v.z - bf2f(h.z));
  h.w = f2bf(v.w); l.w = f2bf(v.w - bf2f(h.w));
  ((short4v*)hi)[i] = h;
  ((short4v*)lo)[i] = l;
}

// ============ bf16-pair MFMA GEMM: C[M,N] = (Ah+Al)[M,K] @ (Bh+Bl)[N,K]^T ============
// WPAIR: epilogue also emits bf16 hi/lo pairs of C (fused split for next GEMM).
template <int BM, int BN, bool WPAIR>
__global__ __launch_bounds__(256) void k_gemm_bfp(
    const short* __restrict__ Ahg, const short* __restrict__ Alg,
    const short* __restrict__ Bhg, const short* __restrict__ Blg,
    float* __restrict__ C, short* __restrict__ Ch, short* __restrict__ Cl,
    int ldc, int K) {
  constexpr int MR = BM / 32, NR = BN / 32;
  __shared__ short Ah[BM][44], Al[BM][44], Bh[BN][44], Bl[BN][44];
  const int tid = threadIdx.x;
  const int w = tid >> 6, lane = tid & 63;
  const int wr = w >> 1, wc = w & 1;
  const int r16 = lane & 15, kh = lane >> 4;
  const int m0 = blockIdx.x * BM, n0 = blockIdx.y * BN;

  f32x4 acc[MR][NR];
  #pragma unroll
  for (int i = 0; i < MR; ++i)
    #pragma unroll
    for (int j = 0; j < NR; ++j) {
      acc[i][j][0] = 0.f; acc[i][j][1] = 0.f; acc[i][j][2] = 0.f; acc[i][j][3] = 0.f;
    }

  for (int k0 = 0; k0 < K; k0 += 32) {
    __syncthreads();
    #pragma unroll
    for (int p = 0; p < BM / 64; ++p) {
      int f = tid + p * 256;                 // BM*4 short8s per operand
      int r = f >> 2, c8 = (f & 3) << 3;
      size_t g = (size_t)(m0 + r) * K + k0 + c8;
      store8(&Ah[r][c8], *(const short8v*)(Ahg + g));
      store8(&Al[r][c8], *(const short8v*)(Alg + g));
    }
    #pragma unroll
    for (int p = 0; p < BN / 64; ++p) {
      int f = tid + p * 256;
      int r = f >> 2, c8 = (f & 3) << 3;
      size_t g = (size_t)(n0 + r) * K + k0 + c8;
      store8(&Bh[r][c8], *(const short8v*)(Bhg + g));
      store8(&Bl[r][c8], *(const short8v*)(Blg + g));
    }
    __syncthreads();
    short8v ah[MR], al[MR], bh[NR], bl[NR];
    #pragma unroll
    for (int i = 0; i < MR; ++i) {
      int rr = wr * (BM / 2) + i * 16 + r16;
      ah[i] = *(const short8v*)(&Ah[rr][kh * 8]);
      al[i] = *(const short8v*)(&Al[rr][kh * 8]);
    }
    #pragma unroll
    for (int j = 0; j < NR; ++j) {
      int cc = wc * (BN / 2) + j * 16 + r16;
      bh[j] = *(const short8v*)(&Bh[cc][kh * 8]);
      bl[j] = *(const short8v*)(&Bl[cc][kh * 8]);
    }
    #pragma unroll
    for (int i = 0; i < MR; ++i)
      #pragma unroll
      for (int j = 0; j < NR; ++j) {
        acc[i][j] = __builtin_amdgcn_mfma_f32_16x16x32_bf16(ah[i], bh[j], acc[i][j], 0, 0, 0);
        acc[i][j] = __builtin_amdgcn_mfma_f32_16x16x32_bf16(ah[i], bl[j], acc[i][j], 0, 0, 0);
        acc[i][j] = __builtin_amdgcn_mfma_f32_16x16x32_bf16(al[i], bh[j], acc[i][j], 0, 0, 0);
      }
  }
  #pragma unroll
  for (int i = 0; i < MR; ++i) {
    int row_base = m0 + wr * (BM / 2) + i * 16 + kh * 4;   // D: col=lane&15, row=(lane>>4)*4+reg
    #pragma unroll
    for (int j = 0; j < NR; ++j) {
      int col = n0 + wc * (BN / 2) + j * 16 + r16;
      #pragma unroll
      for (int r = 0; r < 4; ++r) {
        float v = acc[i][j][r];
        size_t o = (size_t)(row_base + r) * ldc + col;
        C[o] = v;
        if constexpr (WPAIR) {
          short h = f2bf(v);
          Ch[o] = h;
          Cl[o] = f2bf(v - bf2f(h));
        }
      }
    }
  }
}

// ============ x_proj split-K bf16x3 MFMA (fp32 input, in-kernel split) ============
template <int SK>
__global__ __launch_bounds__(256) void k_xproj_mfma(
    const float* __restrict__ A,      // XB [4096][1024]
    const float* __restrict__ W,      // Wx [64][1024]
    float* __restrict__ PART) {       // [SK][4096][64]
  constexpr int BM = 128, BN = 64, KS = 1024 / SK;
  constexpr int MR = 4, NR = 2;       // wave tile 64x32
  __shared__ short Ah[BM][44], Al[BM][44], Bh[BN][44], Bl[BN][44];
  const int tid = threadIdx.x;
  const int w = tid >> 6, lane = tid & 63;
  const int wr = w >> 1, wc = w & 1;
  const int r16 = lane & 15, kh = lane >> 4;
  const int m0 = blockIdx.x * BM;
  const int kbeg = blockIdx.z * KS;

  f32x4 acc[MR][NR];
  #pragma unroll
  for (int i = 0; i < MR; ++i)
    #pragma unroll
    for (int j = 0; j < NR; ++j) {
      acc[i][j][0] = 0.f; acc[i][j][1] = 0.f; acc[i][j][2] = 0.f; acc[i][j][3] = 0.f;
    }

  for (int k0 = kbeg; k0 < kbeg + KS; k0 += 32) {
    __syncthreads();
    #pragma unroll
    for (int p = 0; p < BM / 32; ++p) {
      int f = tid + p * 256;
      int r = f >> 3, c = (f & 7) << 2;
      const float4 v = *(const float4*)(A + (size_t)(m0 + r) * 1024 + k0 + c);
      short h0 = f2bf(v.x), h1 = f2bf(v.y), h2 = f2bf(v.z), h3 = f2bf(v.w);
      Ah[r][c + 0] = h0; Ah[r][c + 1] = h1; Ah[r][c + 2] = h2; Ah[r][c + 3] = h3;
      Al[r][c + 0] = f2bf(v.x - bf2f(h0));
      Al[r][c + 1] = f2bf(v.y - bf2f(h1));
      Al[r][c + 2] = f2bf(v.z - bf2f(h2));
      Al[r][c + 3] = f2bf(v.w - bf2f(h3));
    }
    #pragma unroll
    for (int p = 0; p < BN / 32; ++p) {
      int f = tid + p * 256;
      int r = f >> 3, c = (f & 7) << 2;
      const float4 v = *(const float4*)(W + (size_t)r * 1024 + k0 + c);
      short h0 = f2bf(v.x), h1 = f2bf(v.y), h2 = f2bf(v.z), h3 = f2bf(v.w);
      Bh[r][c + 0] = h0; Bh[r][c + 1] = h1; Bh[r][c + 2] = h2; Bh[r][c + 3] = h3;
      Bl[r][c + 0] = f2bf(v.x - bf2f(h0));
      Bl[r][c + 1] = f2bf(v.y - bf2f(h1));
      Bl[r][c + 2] = f2bf(v.z - bf2f(h2));
      Bl[r][c + 3] = f2bf(v.w - bf2f(h3));
    }
    __syncthreads();
    short8v ah[MR], al[MR], bh[NR], bl[NR];
    #pragma unroll
    for (int i = 0; i < MR; ++i) {
      int rr = wr * 64 + i * 16 + r16;
      ah[i] = *(const short8v*)(&Ah[rr][kh * 8]);
      al[i] = *(const short8v*)(&Al[rr][kh * 8]);
    }
    #pragma unroll
    for (int j = 0; j < NR; ++j) {
      int cc = wc * 32 + j * 16 + r16;
      bh[j] = *(const short8v*)(&Bh[cc][kh * 8]);
      bl[j] = *(const short8v*)(&Bl[cc][kh * 8]);
    }
    #pragma unroll
    for (int i = 0; i < MR; ++i)
      #pragma unroll
      for (int j = 0; j < NR; ++j) {
        acc[i][j] = __builtin_amdgcn_mfma_f32_16x16x32_bf16(ah[i], bh[j], acc[i][j], 0, 0, 0);
        acc[i][j] = __builtin_amdgcn_mfma_f32_16x16x32_bf16(ah[i], bl[j], acc[i][j], 0, 0, 0);
        acc[i][j] = __builtin_amdgcn_mfma_f32_16x16x32_bf16(al[i], bh[j], acc[i][j], 0, 0, 0);
      }
  }
  float* Cp = PART + (size_t)blockIdx.z * (4096 * 64);
  #pragma unroll
  for (int i = 0; i < MR; ++i) {
    int row_base = m0 + wr * 64 + i * 16 + kh * 4;
    #pragma unroll
    for (int j = 0; j < NR; ++j) {
      int col = wc * 32 + j * 16 + r16;
      #pragma unroll
      for (int r = 0; r < 4; ++r)
        Cp[(size_t)(row_base + r) * 64 + col] = acc[i][j][r];
    }
  }
}

template <int SK>
__global__ __launch_bounds__(256) void k_redux(const float* __restrict__ PART,
                                               float* __restrict__ out) {
  int i = blockIdx.x * 256 + threadIdx.x;      // over 4096*64/4 float4s
  float4 s = ((const float4*)PART)[i];
  #pragma unroll
  for (int k = 1; k < SK; ++k) {
    const float4 v = ((const float4*)PART)[i + k * 65536];
    s.x += v.x; s.y += v.y; s.z += v.z; s.w += v.w;
  }
  ((float4*)out)[i] = s;
}

// ---------------- generic fp32 GEMM (kept for dt_proj) ----------------
template <int BM, int BN, int EPI>
__global__ __launch_bounds__(256) void k_gemm_tn(
    const float* __restrict__ A, int lda,
    const float* __restrict__ W, int ldw,
    const float* __restrict__ bias,
    float* __restrict__ C, int ldc, int K) {
  constexpr int BK = 16;
  constexpr int MR = BM / 16, NR = BN / 16;
  __shared__ float As[BK][BM + 4];
  __shared__ float Bs[BK][BN + 4];
  const int tid = threadIdx.x;
  const int tx = tid & 15, ty = tid >> 4;
  const int m0 = blockIdx.x * BM, n0 = blockIdx.y * BN;
  const int arow = tid >> 2;
  const int akol = (tid & 3) << 2;
  float acc[MR][NR] = {};
  for (int k0 = 0; k0 < K; k0 += BK) {
    #pragma unroll
    for (int r = 0; r < BM / 64; ++r) {
      int m = arow + r * 64;
      const float4 v = *(const float4*)(A + (size_t)(m0 + m) * lda + k0 + akol);
      As[akol + 0][m] = v.x; As[akol + 1][m] = v.y;
      As[akol + 2][m] = v.z; As[akol + 3][m] = v.w;
    }
    if constexpr (BN >= 64) {
      #pragma unroll
      for (int r = 0; r < BN / 64; ++r) {
        int n = arow + r * 64;
        const float4 v = *(const float4*)(W + (size_t)(n0 + n) * ldw + k0 + akol);
        Bs[akol + 0][n] = v.x; Bs[akol + 1][n] = v.y;
        Bs[akol + 2][n] = v.z; Bs[akol + 3][n] = v.w;
      }
    } else {
      if (arow < BN) {
        const float4 v = *(const float4*)(W + (size_t)(n0 + arow) * ldw + k0 + akol);
        Bs[akol + 0][arow] = v.x; Bs[akol + 1][arow] = v.y;
        Bs[akol + 2][arow] = v.z; Bs[akol + 3][arow] = v.w;
      }
    }
    __syncthreads();
    #pragma unroll
    for (int k = 0; k < BK; ++k) {
      float af[MR], bf[NR];
      #pragma unroll
      for (int i = 0; i < MR; ++i) af[i] = As[k][ty * MR + i];
      #pragma unroll
      for (int j = 0; j < NR; ++j) bf[j] = Bs[k][tx * NR + j];
      #pragma unroll
      for (int i = 0; i < MR; ++i)
        #pragma unroll
        for (int j = 0; j < NR; ++j)
          acc[i][j] = fmaf(af[i], bf[j], acc[i][j]);
    }
    __syncthreads();
  }
  #pragma unroll
  for (int i = 0; i < MR; ++i) {
    int m = m0 + ty * MR + i;
    #pragma unroll
    for (int j = 0; j < NR; ++j) {
      int n = n0 + tx * NR + j;
      float v = acc[i][j];
      if constexpr (EPI == 1) {
        v += bias[n];
        v = (v > 20.f) ? v : log1pf(__expf(v));
      }
      C[(size_t)m * ldc + n] = v;
    }
  }
}

// ---------------- causal depthwise conv (D_CONV=4) + bias + silu, x4 vectorized ----------------
__global__ __launch_bounds__(256) void k_conv_silu4(const float* __restrict__ xz,
    const float* __restrict__ cw, const float* __restrict__ cb, float* __restrict__ xb) {
  int idx = blockIdx.x * 256 + threadIdx.x;    // over B*L*ED/4
  int e4 = (idx & 255) << 2;                   // e base
  int bl = idx >> 8;
  int l = bl & (Lx - 1);
  const float4 w0 = ((const float4*)cw)[e4 + 0];
  const float4 w1 = ((const float4*)cw)[e4 + 1];
  const float4 w2 = ((const float4*)cw)[e4 + 2];
  const float4 w3 = ((const float4*)cw)[e4 + 3];
  float4 acc = ((const float4*)cb)[idx & 255];
  const float* base = xz + (size_t)bl * (2 * EDx) + e4;
  if (l >= 3) { const float4 x = *(const float4*)(base - 3 * 2 * EDx);
    acc.x = fmaf(x.x, w0.x, acc.x); acc.y = fmaf(x.y, w1.x, acc.y);
    acc.z = fmaf(x.z, w2.x, acc.z); acc.w = fmaf(x.w, w3.x, acc.w); }
  if (l >= 2) { const float4 x = *(const float4*)(base - 2 * 2 * EDx);
    acc.x = fmaf(x.x, w0.y, acc.x); acc.y = fmaf(x.y, w1.y, acc.y);
    acc.z = fmaf(x.z, w2.y, acc.z); acc.w = fmaf(x.w, w3.y, acc.w); }
  if (l >= 1) { const float4 x = *(const float4*)(base - 1 * 2 * EDx);
    acc.x = fmaf(x.x, w0.z, acc.x); acc.y = fmaf(x.y, w1.z, acc.y);
    acc.z = fmaf(x.z, w2.z, acc.z); acc.w = fmaf(x.w, w3.z, acc.w); }
  { const float4 x = *(const float4*)(base);
    acc.x = fmaf(x.x, w0.w, acc.x); acc.y = fmaf(x.y, w1.w, acc.y);
    acc.z = fmaf(x.z, w2.w, acc.z); acc.w = fmaf(x.w, w3.w, acc.w); }
  acc.x /= (1.f + __expf(-acc.x));
  acc.y /= (1.f + __expf(-acc.y));
  acc.z /= (1.f + __expf(-acc.z));
  acc.w /= (1.f + __expf(-acc.w));
  ((float4*)xb)[idx] = acc;
}

// ==================== chunked selective scan (templated on chunk count) ====================
#define CVT4(V) { V.x = -__expf(V.x) * 1.44269504f; V.y = -__expf(V.y) * 1.44269504f; \
                  V.z = -__expf(V.z) * 1.44269504f; V.w = -__expf(V.w) * 1.44269504f; }

#define ST4PQ(Av, Pv, Qv, Bv) { \
  float a0 = exp2f(dl * Av.x); Pv.x *= a0; Qv.x = fmaf(a0, Qv.x, dx * Bv.x); \
  float a1 = exp2f(dl * Av.y); Pv.y *= a1; Qv.y = fmaf(a1, Qv.y, dx * Bv.y); \
  float a2 = exp2f(dl * Av.z); Pv.z *= a2; Qv.z = fmaf(a2, Qv.z, dx * Bv.z); \
  float a3 = exp2f(dl * Av.w); Pv.w *= a3; Qv.w = fmaf(a3, Qv.w, dx * Bv.w); }

#define ST4Y(Av, Hv, Bv, Cv) { \
  float a0 = exp2f(dl * Av.x); Hv.x = fmaf(a0, Hv.x, dx * Bv.x); y = fmaf(Hv.x, Cv.x, y); \
  float a1 = exp2f(dl * Av.y); Hv.y = fmaf(a1, Hv.y, dx * Bv.y); y = fmaf(Hv.y, Cv.y, y); \
  float a2 = exp2f(dl * Av.z); Hv.z = fmaf(a2, Hv.z, dx * Bv.z); y = fmaf(Hv.z, Cv.z, y); \
  float a3 = exp2f(dl * Av.w); Hv.w = fmaf(a3, Hv.w, dx * Bv.w); y = fmaf(Hv.w, Cv.w, y); }

template <int NCt>
__global__ __launch_bounds__(256) void k_scan1(
    const float* __restrict__ del, const float* __restrict__ xb,
    const float* __restrict__ dbc, const float* __restrict__ Alog,
    float* __restrict__ PQ) {
  constexpr int CTt = Lx / NCt;
  const int idx = blockIdx.x * 256 + threadIdx.x;   // c*4096 + ch
  const int ch = idx & 4095, c = idx >> 12;
  const int b = ch >> 10, e = ch & 1023;
  float4 A0, A1, A2, A3;
  {
    const float4* ar = (const float4*)(Alog + e * DS);
    A0 = ar[0]; A1 = ar[1]; A2 = ar[2]; A3 = ar[3];
    CVT4(A0); CVT4(A1); CVT4(A2); CVT4(A3);
  }
  float4 P0 = {1,1,1,1}, P1 = {1,1,1,1}, P2 = {1,1,1,1}, P3 = {1,1,1,1};
  float4 Q0 = {0,0,0,0}, Q1 = {0,0,0,0}, Q2 = {0,0,0,0}, Q3 = {0,0,0,0};
  const size_t bl0 = (size_t)b * Lx + c * CTt;
  const float* dp  = del + bl0 * EDx + e;
  const float* xp  = xb  + bl0 * EDx + e;
  const float* bcp = dbc + bl0 * 64 + 32;
  #pragma unroll 2
  for (int i = 0; i < CTt; ++i) {
    float dl = dp[0];
    float xbl = xp[0];
    float dx = dl * xbl;
    const float4* bp = (const float4*)bcp;
    float4 B0 = bp[0], B1 = bp[1], B2 = bp[2], B3 = bp[3];
    ST4PQ(A0, P0, Q0, B0); ST4PQ(A1, P1, Q1, B1);
    ST4PQ(A2, P2, Q2, B2); ST4PQ(A3, P3, Q3, B3);
    dp += EDx; xp += EDx; bcp += 64;
  }
  float4* o = (float4*)(PQ + (size_t)idx * 32);
  o[0] = P0; o[1] = P1; o[2] = P2; o[3] = P3;
  o[4] = Q0; o[5] = Q1; o[6] = Q2; o[7] = Q3;
}

// Pass 2: sequential combine over chunks, 8-deep two-bank software pipeline.
template <int NCt>
__global__ __launch_bounds__(256) void k_scan2(float* __restrict__ PQ) {
  const int idx = blockIdx.x * 256 + threadIdx.x;   // ch*16 + n
  const int ch = idx >> 4, n = idx & 15;
  constexpr int G = 8;
  const size_t off = (size_t)ch * 32 + n;
  float Pa[G], Qa[G], Pb[G], Qb[G];
  #pragma unroll
  for (int j = 0; j < G; ++j) {
    size_t base = (size_t)j * (4096 * 32) + off;
    Pa[j] = PQ[base]; Qa[j] = PQ[base + 16];
  }
  float H = 0.f;
  #pragma unroll
  for (int gp = 0; gp < NCt / (2 * G); ++gp) {
    const int cA = 2 * gp * G, cB = (2 * gp + 1) * G, cN = (2 * gp + 2) * G;
    #pragma unroll
    for (int j = 0; j < G; ++j) {
      size_t base = (size_t)(cB + j) * (4096 * 32) + off;
      Pb[j] = PQ[base]; Qb[j] = PQ[base + 16];
    }
    #pragma unroll
    for (int j = 0; j < G; ++j) {
      size_t base = (size_t)(cA + j) * (4096 * 32) + off;
      PQ[base + 16] = H;                  // carry-in for chunk cA+j
      H = fmaf(Pa[j], H, Qa[j]);
    }
    if (gp + 1 < NCt / (2 * G)) {
      #pragma unroll
      for (int j = 0; j < G; ++j) {
        size_t base = (size_t)(cN + j) * (4096 * 32) + off;
        Pa[j] = PQ[base]; Qa[j] = PQ[base + 16];
      }
    }
    #pragma unroll
    for (int j = 0; j < G; ++j) {
      size_t base = (size_t)(cB + j) * (4096 * 32) + off;
      PQ[base + 16] = H;
      H = fmaf(Pb[j], H, Qb[j]);
    }
  }
}

// Pass 3: recompute interior; y written directly as bf16 hi/lo pairs (feeds out_proj).
template <int NCt>
__global__ __launch_bounds__(256) void k_scan3(
    const float* __restrict__ del,
    const float* __restrict__ xb,
    const float* __restrict__ dbc,
    const float* __restrict__ xz,         // z at column offset ED
    const float* __restrict__ Alog, const float* __restrict__ Dp,
    const float* __restrict__ PQ,
    short* __restrict__ yh, short* __restrict__ yl) {
  constexpr int CTt = Lx / NCt;
  const int idx = blockIdx.x * 256 + threadIdx.x;   // c*4096 + ch
  const int ch = idx & 4095, c = idx >> 12;
  const int b = ch >> 10, e = ch & 1023;
  float4 A0, A1, A2, A3;
  {
    const float4* ar = (const float4*)(Alog + e * DS);
    A0 = ar[0]; A1 = ar[1]; A2 = ar[2]; A3 = ar[3];
    CVT4(A0); CVT4(A1); CVT4(A2); CVT4(A3);
  }
  float4 H0, H1, H2, H3;
  {
    const float4* hi = (const float4*)(PQ + (size_t)idx * 32 + 16);
    H0 = hi[0]; H1 = hi[1]; H2 = hi[2]; H3 = hi[3];
  }
  const float De = Dp[e];
  const size_t bl0 = (size_t)b * Lx + c * CTt;
  const float* dyp = del + bl0 * EDx + e;
  const float* xp  = xb + bl0 * EDx + e;
  const float* bcp = dbc + bl0 * 64 + 32;
  const float* zp  = xz + bl0 * (2 * EDx) + EDx + e;
  short* yhp = yh + bl0 * EDx + e;
  short* ylp = yl + bl0 * EDx + e;
  #pragma unroll 2
  for (int i = 0; i < CTt; ++i) {
    float dl = dyp[0];
    float xbl = xp[0];
    float zv = zp[0];
    float dx = dl * xbl;
    const float4* bp = (const float4*)bcp;
    float4 B0 = bp[0], B1 = bp[1], B2 = bp[2], B3 = bp[3];
    float4 C0 = bp[4], C1 = bp[5], C2 = bp[6], C3 = bp[7];
    float y = 0.f;
    ST4Y(A0, H0, B0, C0); ST4Y(A1, H1, B1, C1);
    ST4Y(A2, H2, B2, C2); ST4Y(A3, H3, B3, C3);
    y = fmaf(De, xbl, y);
    y *= zv / (1.f + __expf(-zv));
    short h = f2bf(y);
    yhp[0] = h;
    ylp[0] = f2bf(y - bf2f(h));
    dyp += EDx; xp += EDx; bcp += 64; zp += 2 * EDx; yhp += EDx; ylp += EDx;
  }
}

// ---------------- last-token LayerNorm + head ----------------
__global__ __launch_bounds__(256) void k_ln_head(
    const float* __restrict__ x, const float* __restrict__ g,
    const float* __restrict__ be, const float* __restrict__ Wo,
    const float* __restrict__ bo, float* __restrict__ out) {
  const int b = blockIdx.x;
  const int t = threadIdx.x;
  const float* xr = x + ((size_t)b * Lx + (Lx - 1)) * DM;
  __shared__ float w1[4], w2[4];
  __shared__ float xn[DM];
  __shared__ float hp[20][8];
  float a0 = xr[t], a1 = xr[t + 256];
  float p = a0 + a1;
  #pragma unroll
  for (int o = 32; o > 0; o >>= 1) p += __shfl_down(p, o);
  if ((t & 63) == 0) w1[t >> 6] = p;
  __syncthreads();
  float mean = (w1[0] + w1[1] + w1[2] + w1[3]) * (1.f / DM);
  float d0 = a0 - mean, d1 = a1 - mean;
  p = d0 * d0 + d1 * d1;
  #pragma unroll
  for (int o = 32; o > 0; o >>= 1) p += __shfl_down(p, o);
  if ((t & 63) == 0) w2[t >> 6] = p;
  __syncthreads();
  float rstd = rsqrtf((w2[0] + w2[1] + w2[2] + w2[3]) * (1.f / DM) + 1e-5f);
  xn[t] = d0 * rstd * g[t] + be[t];
  xn[t + 256] = d1 * rstd * g[t + 256] + be[t + 256];
  __syncthreads();
  if (t < 160) {
    int j = t / 8, sg = t % 8;
    const float* wr = Wo + (size_t)j * DM + sg * 64;
    const float* xs = xn + sg * 64;
    float s = 0.f;
    #pragma unroll
    for (int k = 0; k < 64; ++k) s = fmaf(xs[k], wr[k], s);
    hp[j][sg] = s;
  }
  __syncthreads();
  if (t < 20) {
    float s = bo[t];
    #pragma unroll
    for (int k = 0; k < 8; ++k) s += hp[t][k];
    out[b * 20 + t] = s;
  }
}

extern "C" void kernel_launch(void* const* d_in, const int* in_sizes, int n_in,
                              void* d_out, int out_size, void* d_ws, size_t ws_size,
                              hipStream_t stream) {
  (void)in_sizes; (void)n_in; (void)out_size;
  const float* seq    = (const float*)d_in[0];
  const float* Wi     = (const float*)d_in[1];
  const float* bi     = (const float*)d_in[2];
  const float* Wo     = (const float*)d_in[3];
  const float* bo     = (const float*)d_in[4];
  const float* ln_g   = (const float*)d_in[5];
  const float* ln_b   = (const float*)d_in[6];
  const float* lWin   = (const float*)d_in[7];
  const float* lconvw = (const float*)d_in[8];
  const float* lconvb = (const float*)d_in[9];
  const float* lWx    = (const float*)d_in[10];
  const float* lWdt   = (const float*)d_in[11];
  const float* lbdt   = (const float*)d_in[12];
  const float* lAlog  = (const float*)d_in[13];
  const float* lD     = (const float*)d_in[14];
  const float* lWout  = (const float*)d_in[15];

  float* ws  = (float*)d_ws;
  float* X   = ws;                 // [4096][512]   = 2,097,152 floats
  float* XZ  = X + 2097152;        // [4096][2048]  = 8,388,608
  float* XB  = XZ + 8388608;       // [4096][1024]  = 4,194,304
  float* DBC = XB + 4194304;       // [4096][64]    = 262,144
  float* DEL = DBC + 262144;       // [4096][1024]  = 4,194,304 (delta only now)
  float* PQ  = DEL + 4194304;      // [NC*4096][32] floats; PART aliases (disjoint phase)
  float* PART = PQ;                // [8][4096][64] = 2M floats (xproj phase only)

  // nc64 layout: floats 27,525,120 (110,100,480 B) + shorts 15,728,640 (31,457,280 B)
  //            = 141,557,760 B.  nc32 fallback: 124,780,544 B. (ws observed = 256 MiB)
  const bool nc64 = ws_size >= (size_t)141557760;
  const int  pqf  = nc64 ? 8388608 : 4194304;      // PQ floats actually used

  short* S     = (short*)(PQ + pqf);               // dedicated pair region
  short* Xh    = S;                                // 2,097,152 shorts
  short* Xl    = S + 2097152;
  short* Yh    = S + 4194304;                      // 4,194,304 shorts
  short* Yl    = S + 8388608;
  short* Winh  = S + 12582912;                     // 1,048,576 shorts
  short* Winl  = S + 13631488;
  short* Wouth = S + 14680064;                     // 524,288 shorts
  short* Woutl = S + 15204352;

  k_init_x<<<dim3(Bx * Lx * DM / 256), 256, 0, stream>>>(seq, Wi, bi, X, Xh, Xl);

  for (int i = 0; i < NL; ++i) {
    const float* Win  = lWin   + (size_t)i * 2048 * 512;
    const float* cw   = lconvw + (size_t)i * EDx * 4;
    const float* cb   = lconvb + (size_t)i * EDx;
    const float* Wx   = lWx    + (size_t)i * 64 * EDx;
    const float* Wdt  = lWdt   + (size_t)i * EDx * DTR;
    const float* bdt  = lbdt   + (size_t)i * EDx;
    const float* Alog = lAlog  + (size_t)i * EDx * DS;
    const float* Dp   = lD     + (size_t)i * EDx;
    const float* Wout = lWout  + (size_t)i * DM * EDx;

    // split Win (weights only); xz = x @ Win^T  (pairs already in Xh/Xl)
    k_split<<<dim3(1024), 256, 0, stream>>>(Win, Winh, Winl);
    k_gemm_bfp<128, 128, false><<<dim3(32, 16), 256, 0, stream>>>(
        Xh, Xl, Winh, Winl, XZ, nullptr, nullptr, 2 * EDx, DM);
    // xb = silu(causal_dwconv(xz[:, :ED]) + cb)
    k_conv_silu4<<<dim3(Bx * Lx * EDx / 1024), 256, 0, stream>>>(XZ, cw, cb, XB);
    // dbc = xb @ Wx^T  (split-K MFMA + reduce)
    k_xproj_mfma<8><<<dim3(32, 1, 8), 256, 0, stream>>>(XB, Wx, PART);
    k_redux<8><<<dim3(256), 256, 0, stream>>>(PART, DBC);
    // delta = softplus(dbc[:, :32] @ Wdt^T + bdt)
    k_gemm_tn<128, 64, 1><<<dim3(32, 16), 256, 0, stream>>>(DBC, 64, Wdt, DTR, bdt, DEL, EDx, DTR);
    // chunked selective scan + gating; y emitted as bf16 pairs (Yh/Yl)
    if (nc64) {
      k_scan1<64><<<dim3(4096 * 64 / 256), 256, 0, stream>>>(DEL, XB, DBC, Alog, PQ);
      k_scan2<64><<<dim3(4096 * DS / 256), 256, 0, stream>>>(PQ);
      k_scan3<64><<<dim3(4096 * 64 / 256), 256, 0, stream>>>(DEL, XB, DBC, XZ, Alog, Dp, PQ, Yh, Yl);
    } else {
      k_scan1<32><<<dim3(4096 * 32 / 256), 256, 0, stream>>>(DEL, XB, DBC, Alog, PQ);
      k_scan2<32><<<dim3(4096 * DS / 256), 256, 0, stream>>>(PQ);
      k_scan3<32><<<dim3(4096 * 32 / 256), 256, 0, stream>>>(DEL, XB, DBC, XZ, Alog, Dp, PQ, Yh, Yl);
    }
    // split Wout; x = y @ Wout^T — epilogue emits X fp32 + next layer's Xh/Xl pairs
    k_split<<<dim3(512), 256, 0, stream>>>(Wout, Wouth, Woutl);
    k_gemm_bfp<128, 64, true><<<dim3(32, 8), 256, 0, stream>>>(
        Yh, Yl, Wouth, Woutl, X, Xh, Xl, DM, EDx);
  }

  k_ln_head<<<dim3(Bx), 256, 0, stream>>>(X, ln_g, ln_b, Wo, bo, (float*)d_out);
}

// Round 13
// 842.224 us; speedup vs baseline: 1.1470x; 1.1222x over previous
//
#include <hip/hip_runtime.h>
#include <hip/hip_bf16.h>
#include <math.h>

constexpr int Bx = 4, Lx = 1024, DM = 512, DS = 16, NL = 4, EDx = 1024;
constexpr int DTR = 32;

typedef __attribute__((ext_vector_type(8))) short short8v;   // 8 bf16 = 4 VGPR
typedef __attribute__((ext_vector_type(4))) float f32x4;

__device__ inline short f2bf(float f) {
  union { __hip_bfloat16 h; short s; } u;
  u.h = __float2bfloat16(f);
  return u.s;
}
__device__ inline float bf2f(short s) {
  union { __hip_bfloat16 h; short s; } u;
  u.s = s;
  return __bfloat162float(u.h);
}

// ---------------- x = seq @ Wi^T + bi ----------------
__global__ __launch_bounds__(256) void k_init_x(const float* __restrict__ seq,
    const float* __restrict__ Wi, const float* __restrict__ bi, float* __restrict__ x) {
  int idx = blockIdx.x * 256 + threadIdx.x;      // over B*L*DM
  int d = idx & (DM - 1);
  int bl = idx >> 9;
  float s0 = seq[bl * 3 + 0], s1 = seq[bl * 3 + 1], s2 = seq[bl * 3 + 2];
  x[idx] = bi[d] + s0 * Wi[d * 3 + 0] + s1 * Wi[d * 3 + 1] + s2 * Wi[d * 3 + 2];
}

// ============ split-fp32 (bf16x3) MFMA GEMM: C[M,N] = A[M,K] @ W[N,K]^T ============
// In-kernel hi/lo split (r7-measured 911 structure); 4 waves 2x2; 16x16x32 bf16 MFMA.
template <int BM, int BN>
__global__ __launch_bounds__(256) void k_gemm_mfma(
    const float* __restrict__ A, int lda,
    const float* __restrict__ W, int ldw,
    float* __restrict__ C, int ldc, int K) {
  constexpr int MR = BM / 32, NR = BN / 32;
  __shared__ short Ah[BM][44], Al[BM][44], Bh[BN][44], Bl[BN][44];
  const int tid = threadIdx.x;
  const int w = tid >> 6, lane = tid & 63;
  const int wr = w >> 1, wc = w & 1;
  const int r16 = lane & 15, kh = lane >> 4;
  const int m0 = blockIdx.x * BM, n0 = blockIdx.y * BN;

  f32x4 acc[MR][NR];
  #pragma unroll
  for (int i = 0; i < MR; ++i)
    #pragma unroll
    for (int j = 0; j < NR; ++j) {
      acc[i][j][0] = 0.f; acc[i][j][1] = 0.f; acc[i][j][2] = 0.f; acc[i][j][3] = 0.f;
    }

  for (int k0 = 0; k0 < K; k0 += 32) {
    __syncthreads();
    #pragma unroll
    for (int p = 0; p < BM / 32; ++p) {
      int f = tid + p * 256;
      int r = f >> 3, c = (f & 7) << 2;
      const float4 v = *(const float4*)(A + (size_t)(m0 + r) * lda + k0 + c);
      short h0 = f2bf(v.x), h1 = f2bf(v.y), h2 = f2bf(v.z), h3 = f2bf(v.w);
      Ah[r][c + 0] = h0; Ah[r][c + 1] = h1; Ah[r][c + 2] = h2; Ah[r][c + 3] = h3;
      Al[r][c + 0] = f2bf(v.x - bf2f(h0));
      Al[r][c + 1] = f2bf(v.y - bf2f(h1));
      Al[r][c + 2] = f2bf(v.z - bf2f(h2));
      Al[r][c + 3] = f2bf(v.w - bf2f(h3));
    }
    #pragma unroll
    for (int p = 0; p < BN / 32; ++p) {
      int f = tid + p * 256;
      int r = f >> 3, c = (f & 7) << 2;
      const float4 v = *(const float4*)(W + (size_t)(n0 + r) * ldw + k0 + c);
      short h0 = f2bf(v.x), h1 = f2bf(v.y), h2 = f2bf(v.z), h3 = f2bf(v.w);
      Bh[r][c + 0] = h0; Bh[r][c + 1] = h1; Bh[r][c + 2] = h2; Bh[r][c + 3] = h3;
      Bl[r][c + 0] = f2bf(v.x - bf2f(h0));
      Bl[r][c + 1] = f2bf(v.y - bf2f(h1));
      Bl[r][c + 2] = f2bf(v.z - bf2f(h2));
      Bl[r][c + 3] = f2bf(v.w - bf2f(h3));
    }
    __syncthreads();
    short8v ah[MR], al[MR], bh[NR], bl[NR];
    #pragma unroll
    for (int i = 0; i < MR; ++i) {
      int rr = wr * (BM / 2) + i * 16 + r16;
      ah[i] = *(const short8v*)(&Ah[rr][kh * 8]);
      al[i] = *(const short8v*)(&Al[rr][kh * 8]);
    }
    #pragma unroll
    for (int j = 0; j < NR; ++j) {
      int cc = wc * (BN / 2) + j * 16 + r16;
      bh[j] = *(const short8v*)(&Bh[cc][kh * 8]);
      bl[j] = *(const short8v*)(&Bl[cc][kh * 8]);
    }
    #pragma unroll
    for (int i = 0; i < MR; ++i)
      #pragma unroll
      for (int j = 0; j < NR; ++j) {
        acc[i][j] = __builtin_amdgcn_mfma_f32_16x16x32_bf16(ah[i], bh[j], acc[i][j], 0, 0, 0);
        acc[i][j] = __builtin_amdgcn_mfma_f32_16x16x32_bf16(ah[i], bl[j], acc[i][j], 0, 0, 0);
        acc[i][j] = __builtin_amdgcn_mfma_f32_16x16x32_bf16(al[i], bh[j], acc[i][j], 0, 0, 0);
      }
  }
  #pragma unroll
  for (int i = 0; i < MR; ++i) {
    int row_base = m0 + wr * (BM / 2) + i * 16 + kh * 4;   // D: col=lane&15, row=(lane>>4)*4+reg
    #pragma unroll
    for (int j = 0; j < NR; ++j) {
      int col = n0 + wc * (BN / 2) + j * 16 + r16;
      #pragma unroll
      for (int r = 0; r < 4; ++r)
        C[(size_t)(row_base + r) * ldc + col] = acc[i][j][r];
    }
  }
}

// ============ x_proj split-K bf16x3 MFMA (fp32 input, in-kernel split) ============
template <int SK>
__global__ __launch_bounds__(256) void k_xproj_mfma(
    const float* __restrict__ A,      // XB [4096][1024]
    const float* __restrict__ W,      // Wx [64][1024]
    float* __restrict__ PART) {       // [SK][4096][64]
  constexpr int BM = 128, BN = 64, KS = 1024 / SK;
  constexpr int MR = 4, NR = 2;       // wave tile 64x32
  __shared__ short Ah[BM][44], Al[BM][44], Bh[BN][44], Bl[BN][44];
  const int tid = threadIdx.x;
  const int w = tid >> 6, lane = tid & 63;
  const int wr = w >> 1, wc = w & 1;
  const int r16 = lane & 15, kh = lane >> 4;
  const int m0 = blockIdx.x * BM;
  const int kbeg = blockIdx.z * KS;

  f32x4 acc[MR][NR];
  #pragma unroll
  for (int i = 0; i < MR; ++i)
    #pragma unroll
    for (int j = 0; j < NR; ++j) {
      acc[i][j][0] = 0.f; acc[i][j][1] = 0.f; acc[i][j][2] = 0.f; acc[i][j][3] = 0.f;
    }

  for (int k0 = kbeg; k0 < kbeg + KS; k0 += 32) {
    __syncthreads();
    #pragma unroll
    for (int p = 0; p < BM / 32; ++p) {
      int f = tid + p * 256;
      int r = f >> 3, c = (f & 7) << 2;
      const float4 v = *(const float4*)(A + (size_t)(m0 + r) * 1024 + k0 + c);
      short h0 = f2bf(v.x), h1 = f2bf(v.y), h2 = f2bf(v.z), h3 = f2bf(v.w);
      Ah[r][c + 0] = h0; Ah[r][c + 1] = h1; Ah[r][c + 2] = h2; Ah[r][c + 3] = h3;
      Al[r][c + 0] = f2bf(v.x - bf2f(h0));
      Al[r][c + 1] = f2bf(v.y - bf2f(h1));
      Al[r][c + 2] = f2bf(v.z - bf2f(h2));
      Al[r][c + 3] = f2bf(v.w - bf2f(h3));
    }
    #pragma unroll
    for (int p = 0; p < BN / 32; ++p) {
      int f = tid + p * 256;
      int r = f >> 3, c = (f & 7) << 2;
      const float4 v = *(const float4*)(W + (size_t)r * 1024 + k0 + c);
      short h0 = f2bf(v.x), h1 = f2bf(v.y), h2 = f2bf(v.z), h3 = f2bf(v.w);
      Bh[r][c + 0] = h0; Bh[r][c + 1] = h1; Bh[r][c + 2] = h2; Bh[r][c + 3] = h3;
      Bl[r][c + 0] = f2bf(v.x - bf2f(h0));
      Bl[r][c + 1] = f2bf(v.y - bf2f(h1));
      Bl[r][c + 2] = f2bf(v.z - bf2f(h2));
      Bl[r][c + 3] = f2bf(v.w - bf2f(h3));
    }
    __syncthreads();
    short8v ah[MR], al[MR], bh[NR], bl[NR];
    #pragma unroll
    for (int i = 0; i < MR; ++i) {
      int rr = wr * 64 + i * 16 + r16;
      ah[i] = *(const short8v*)(&Ah[rr][kh * 8]);
      al[i] = *(const short8v*)(&Al[rr][kh * 8]);
    }
    #pragma unroll
    for (int j = 0; j < NR; ++j) {
      int cc = wc * 32 + j * 16 + r16;
      bh[j] = *(const short8v*)(&Bh[cc][kh * 8]);
      bl[j] = *(const short8v*)(&Bl[cc][kh * 8]);
    }
    #pragma unroll
    for (int i = 0; i < MR; ++i)
      #pragma unroll
      for (int j = 0; j < NR; ++j) {
        acc[i][j] = __builtin_amdgcn_mfma_f32_16x16x32_bf16(ah[i], bh[j], acc[i][j], 0, 0, 0);
        acc[i][j] = __builtin_amdgcn_mfma_f32_16x16x32_bf16(ah[i], bl[j], acc[i][j], 0, 0, 0);
        acc[i][j] = __builtin_amdgcn_mfma_f32_16x16x32_bf16(al[i], bh[j], acc[i][j], 0, 0, 0);
      }
  }
  float* Cp = PART + (size_t)blockIdx.z * (4096 * 64);
  #pragma unroll
  for (int i = 0; i < MR; ++i) {
    int row_base = m0 + wr * 64 + i * 16 + kh * 4;
    #pragma unroll
    for (int j = 0; j < NR; ++j) {
      int col = wc * 32 + j * 16 + r16;
      #pragma unroll
      for (int r = 0; r < 4; ++r)
        Cp[(size_t)(row_base + r) * 64 + col] = acc[i][j][r];
    }
  }
}

template <int SK>
__global__ __launch_bounds__(256) void k_redux(const float* __restrict__ PART,
                                               float* __restrict__ out) {
  int i = blockIdx.x * 256 + threadIdx.x;      // over 4096*64/4 float4s
  float4 s = ((const float4*)PART)[i];
  #pragma unroll
  for (int k = 1; k < SK; ++k) {
    const float4 v = ((const float4*)PART)[i + k * 65536];
    s.x += v.x; s.y += v.y; s.z += v.z; s.w += v.w;
  }
  ((float4*)out)[i] = s;
}

// ---------------- generic fp32 GEMM (kept for dt_proj) ----------------
template <int BM, int BN, int EPI>
__global__ __launch_bounds__(256) void k_gemm_tn(
    const float* __restrict__ A, int lda,
    const float* __restrict__ W, int ldw,
    const float* __restrict__ bias,
    float* __restrict__ C, int ldc, int K) {
  constexpr int BK = 16;
  constexpr int MR = BM / 16, NR = BN / 16;
  __shared__ float As[BK][BM + 4];
  __shared__ float Bs[BK][BN + 4];
  const int tid = threadIdx.x;
  const int tx = tid & 15, ty = tid >> 4;
  const int m0 = blockIdx.x * BM, n0 = blockIdx.y * BN;
  const int arow = tid >> 2;
  const int akol = (tid & 3) << 2;
  float acc[MR][NR] = {};
  for (int k0 = 0; k0 < K; k0 += BK) {
    #pragma unroll
    for (int r = 0; r < BM / 64; ++r) {
      int m = arow + r * 64;
      const float4 v = *(const float4*)(A + (size_t)(m0 + m) * lda + k0 + akol);
      As[akol + 0][m] = v.x; As[akol + 1][m] = v.y;
      As[akol + 2][m] = v.z; As[akol + 3][m] = v.w;
    }
    if constexpr (BN >= 64) {
      #pragma unroll
      for (int r = 0; r < BN / 64; ++r) {
        int n = arow + r * 64;
        const float4 v = *(const float4*)(W + (size_t)(n0 + n) * ldw + k0 + akol);
        Bs[akol + 0][n] = v.x; Bs[akol + 1][n] = v.y;
        Bs[akol + 2][n] = v.z; Bs[akol + 3][n] = v.w;
      }
    } else {
      if (arow < BN) {
        const float4 v = *(const float4*)(W + (size_t)(n0 + arow) * ldw + k0 + akol);
        Bs[akol + 0][arow] = v.x; Bs[akol + 1][arow] = v.y;
        Bs[akol + 2][arow] = v.z; Bs[akol + 3][arow] = v.w;
      }
    }
    __syncthreads();
    #pragma unroll
    for (int k = 0; k < BK; ++k) {
      float af[MR], bf[NR];
      #pragma unroll
      for (int i = 0; i < MR; ++i) af[i] = As[k][ty * MR + i];
      #pragma unroll
      for (int j = 0; j < NR; ++j) bf[j] = Bs[k][tx * NR + j];
      #pragma unroll
      for (int i = 0; i < MR; ++i)
        #pragma unroll
        for (int j = 0; j < NR; ++j)
          acc[i][j] = fmaf(af[i], bf[j], acc[i][j]);
    }
    __syncthreads();
  }
  #pragma unroll
  for (int i = 0; i < MR; ++i) {
    int m = m0 + ty * MR + i;
    #pragma unroll
    for (int j = 0; j < NR; ++j) {
      int n = n0 + tx * NR + j;
      float v = acc[i][j];
      if constexpr (EPI == 1) {
        v += bias[n];
        v = (v > 20.f) ? v : log1pf(__expf(v));
      }
      C[(size_t)m * ldc + n] = v;
    }
  }
}

// ---------------- causal depthwise conv (D_CONV=4) + bias + silu, x4 vectorized ----------------
__global__ __launch_bounds__(256) void k_conv_silu4(const float* __restrict__ xz,
    const float* __restrict__ cw, const float* __restrict__ cb, float* __restrict__ xb) {
  int idx = blockIdx.x * 256 + threadIdx.x;    // over B*L*ED/4
  int e4 = (idx & 255) << 2;                   // e base
  int bl = idx >> 8;
  int l = bl & (Lx - 1);
  const float4 w0 = ((const float4*)cw)[e4 + 0];
  const float4 w1 = ((const float4*)cw)[e4 + 1];
  const float4 w2 = ((const float4*)cw)[e4 + 2];
  const float4 w3 = ((const float4*)cw)[e4 + 3];
  float4 acc = ((const float4*)cb)[idx & 255];
  const float* base = xz + (size_t)bl * (2 * EDx) + e4;
  if (l >= 3) { const float4 x = *(const float4*)(base - 3 * 2 * EDx);
    acc.x = fmaf(x.x, w0.x, acc.x); acc.y = fmaf(x.y, w1.x, acc.y);
    acc.z = fmaf(x.z, w2.x, acc.z); acc.w = fmaf(x.w, w3.x, acc.w); }
  if (l >= 2) { const float4 x = *(const float4*)(base - 2 * 2 * EDx);
    acc.x = fmaf(x.x, w0.y, acc.x); acc.y = fmaf(x.y, w1.y, acc.y);
    acc.z = fmaf(x.z, w2.y, acc.z); acc.w = fmaf(x.w, w3.y, acc.w); }
  if (l >= 1) { const float4 x = *(const float4*)(base - 1 * 2 * EDx);
    acc.x = fmaf(x.x, w0.z, acc.x); acc.y = fmaf(x.y, w1.z, acc.y);
    acc.z = fmaf(x.z, w2.z, acc.z); acc.w = fmaf(x.w, w3.z, acc.w); }
  { const float4 x = *(const float4*)(base);
    acc.x = fmaf(x.x, w0.w, acc.x); acc.y = fmaf(x.y, w1.w, acc.y);
    acc.z = fmaf(x.z, w2.w, acc.z); acc.w = fmaf(x.w, w3.w, acc.w); }
  acc.x /= (1.f + __expf(-acc.x));
  acc.y /= (1.f + __expf(-acc.y));
  acc.z /= (1.f + __expf(-acc.z));
  acc.w /= (1.f + __expf(-acc.w));
  ((float4*)xb)[idx] = acc;
}

// ==================== chunked selective scan, 2 lanes per chain (8 states/lane) ====================
#define CVT4(V) { V.x = -__expf(V.x) * 1.44269504f; V.y = -__expf(V.y) * 1.44269504f; \
                  V.z = -__expf(V.z) * 1.44269504f; V.w = -__expf(V.w) * 1.44269504f; }

#define ST4PQ(Av, Pv, Qv, Bv) { \
  float a0 = exp2f(dl * Av.x); Pv.x *= a0; Qv.x = fmaf(a0, Qv.x, dx * Bv.x); \
  float a1 = exp2f(dl * Av.y); Pv.y *= a1; Qv.y = fmaf(a1, Qv.y, dx * Bv.y); \
  float a2 = exp2f(dl * Av.z); Pv.z *= a2; Qv.z = fmaf(a2, Qv.z, dx * Bv.z); \
  float a3 = exp2f(dl * Av.w); Pv.w *= a3; Qv.w = fmaf(a3, Qv.w, dx * Bv.w); }

#define ST4Y(Av, Hv, Bv, Cv) { \
  float a0 = exp2f(dl * Av.x); Hv.x = fmaf(a0, Hv.x, dx * Bv.x); y = fmaf(Hv.x, Cv.x, y); \
  float a1 = exp2f(dl * Av.y); Hv.y = fmaf(a1, Hv.y, dx * Bv.y); y = fmaf(Hv.y, Cv.y, y); \
  float a2 = exp2f(dl * Av.z); Hv.z = fmaf(a2, Hv.z, dx * Bv.z); y = fmaf(Hv.z, Cv.z, y); \
  float a3 = exp2f(dl * Av.w); Hv.w = fmaf(a3, Hv.w, dx * Bv.w); y = fmaf(Hv.w, Cv.w, y); }

// Pass 1: thread = (chunk c, chain ch, half hh); 8 states in registers.
template <int NCt>
__global__ __launch_bounds__(256) void k_scan1(
    const float* __restrict__ del, const float* __restrict__ xb,
    const float* __restrict__ dbc, const float* __restrict__ Alog,
    float* __restrict__ PQ) {
  constexpr int CTt = Lx / NCt;
  const int idx = blockIdx.x * 256 + threadIdx.x;   // over NCt*4096*2
  const int h8 = (idx & 1) << 3;
  const int g = idx >> 1;                           // c*4096 + ch
  const int ch = g & 4095, c = g >> 12;
  const int b = ch >> 10, e = ch & 1023;
  float4 A0, A1;
  {
    const float4* ar = (const float4*)(Alog + e * DS + h8);
    A0 = ar[0]; A1 = ar[1];
    CVT4(A0); CVT4(A1);
  }
  float4 P0 = {1,1,1,1}, P1 = {1,1,1,1};
  float4 Q0 = {0,0,0,0}, Q1 = {0,0,0,0};
  const size_t bl0 = (size_t)b * Lx + c * CTt;
  const float* dp  = del + bl0 * EDx + e;
  const float* xp  = xb  + bl0 * EDx + e;
  const float* bcp = dbc + bl0 * 64 + 32 + h8;
  #pragma unroll 4
  for (int i = 0; i < CTt; ++i) {
    float dl = dp[0];
    float xbl = xp[0];
    float dx = dl * xbl;
    const float4* bp = (const float4*)bcp;
    float4 B0 = bp[0], B1 = bp[1];
    ST4PQ(A0, P0, Q0, B0); ST4PQ(A1, P1, Q1, B1);
    dp += EDx; xp += EDx; bcp += 64;
  }
  float4* o = (float4*)(PQ + (size_t)g * 32 + h8);  // P at n0, Q at 16+n0
  o[0] = P0; o[1] = P1;
  o[4] = Q0; o[5] = Q1;
}

// Pass 2: sequential combine over chunks, 8-deep two-bank software pipeline (unchanged).
template <int NCt>
__global__ __launch_bounds__(256) void k_scan2(float* __restrict__ PQ) {
  const int idx = blockIdx.x * 256 + threadIdx.x;   // ch*16 + n
  const int ch = idx >> 4, n = idx & 15;
  constexpr int G = 8;
  const size_t off = (size_t)ch * 32 + n;
  float Pa[G], Qa[G], Pb[G], Qb[G];
  #pragma unroll
  for (int j = 0; j < G; ++j) {
    size_t base = (size_t)j * (4096 * 32) + off;
    Pa[j] = PQ[base]; Qa[j] = PQ[base + 16];
  }
  float H = 0.f;
  #pragma unroll
  for (int gp = 0; gp < NCt / (2 * G); ++gp) {
    const int cA = 2 * gp * G, cB = (2 * gp + 1) * G, cN = (2 * gp + 2) * G;
    #pragma unroll
    for (int j = 0; j < G; ++j) {
      size_t base = (size_t)(cB + j) * (4096 * 32) + off;
      Pb[j] = PQ[base]; Qb[j] = PQ[base + 16];
    }
    #pragma unroll
    for (int j = 0; j < G; ++j) {
      size_t base = (size_t)(cA + j) * (4096 * 32) + off;
      PQ[base + 16] = H;                  // carry-in for chunk cA+j
      H = fmaf(Pa[j], H, Qa[j]);
    }
    if (gp + 1 < NCt / (2 * G)) {
      #pragma unroll
      for (int j = 0; j < G; ++j) {
        size_t base = (size_t)(cN + j) * (4096 * 32) + off;
        Pa[j] = PQ[base]; Qa[j] = PQ[base + 16];
      }
    }
    #pragma unroll
    for (int j = 0; j < G; ++j) {
      size_t base = (size_t)(cB + j) * (4096 * 32) + off;
      PQ[base + 16] = H;
      H = fmaf(Pb[j], H, Qb[j]);
    }
  }
}

// Pass 3: 2 lanes/chain; y = partial(8) + shfl_xor pair-sum; in-place over delta.
template <int NCt>
__global__ __launch_bounds__(256) void k_scan3(
    float* __restrict__ dy,               // in: delta, out: y (in place)
    const float* __restrict__ xb,
    const float* __restrict__ dbc,
    const float* __restrict__ xz,         // z at column offset ED
    const float* __restrict__ Alog, const float* __restrict__ Dp,
    const float* __restrict__ PQ) {
  constexpr int CTt = Lx / NCt;
  const int idx = blockIdx.x * 256 + threadIdx.x;   // over NCt*4096*2
  const int hh = idx & 1;
  const int h8 = hh << 3;
  const int g = idx >> 1;
  const int ch = g & 4095, c = g >> 12;
  const int b = ch >> 10, e = ch & 1023;
  float4 A0, A1;
  {
    const float4* ar = (const float4*)(Alog + e * DS + h8);
    A0 = ar[0]; A1 = ar[1];
    CVT4(A0); CVT4(A1);
  }
  float4 H0, H1;
  {
    const float4* hi = (const float4*)(PQ + (size_t)g * 32 + 16 + h8);
    H0 = hi[0]; H1 = hi[1];
  }
  const float De = Dp[e];
  const size_t bl0 = (size_t)b * Lx + c * CTt;
  float* dyp = dy + bl0 * EDx + e;
  const float* xp  = xb + bl0 * EDx + e;
  const float* bcp = dbc + bl0 * 64 + 32 + h8;      // B at +0..8, C at +16..24 (float4: bp[4],bp[5])
  const float* zp  = xz + bl0 * (2 * EDx) + EDx + e;
  #pragma unroll 4
  for (int i = 0; i < CTt; ++i) {
    float dl = dyp[0];
    float xbl = xp[0];
    float zv = zp[0];
    float dx = dl * xbl;
    const float4* bp = (const float4*)bcp;
    float4 B0 = bp[0], B1 = bp[1];
    float4 C0 = bp[4], C1 = bp[5];
    float y = 0.f;
    ST4Y(A0, H0, B0, C0); ST4Y(A1, H1, B1, C1);
    y += __shfl_xor(y, 1);                 // pair-sum across the chain's two lanes
    y = fmaf(De, xbl, y);
    y *= zv / (1.f + __expf(-zv));
    if (hh == 0) dyp[0] = y;
    dyp += EDx; xp += EDx; bcp += 64; zp += 2 * EDx;
  }
}

// ---------------- last-token LayerNorm + head ----------------
__global__ __launch_bounds__(256) void k_ln_head(
    const float* __restrict__ x, const float* __restrict__ g,
    const float* __restrict__ be, const float* __restrict__ Wo,
    const float* __restrict__ bo, float* __restrict__ out) {
  const int b = blockIdx.x;
  const int t = threadIdx.x;
  const float* xr = x + ((size_t)b * Lx + (Lx - 1)) * DM;
  __shared__ float w1[4], w2[4];
  __shared__ float xn[DM];
  __shared__ float hp[20][8];
  float a0 = xr[t], a1 = xr[t + 256];
  float p = a0 + a1;
  #pragma unroll
  for (int o = 32; o > 0; o >>= 1) p += __shfl_down(p, o);
  if ((t & 63) == 0) w1[t >> 6] = p;
  __syncthreads();
  float mean = (w1[0] + w1[1] + w1[2] + w1[3]) * (1.f / DM);
  float d0 = a0 - mean, d1 = a1 - mean;
  p = d0 * d0 + d1 * d1;
  #pragma unroll
  for (int o = 32; o > 0; o >>= 1) p += __shfl_down(p, o);
  if ((t & 63) == 0) w2[t >> 6] = p;
  __syncthreads();
  float rstd = rsqrtf((w2[0] + w2[1] + w2[2] + w2[3]) * (1.f / DM) + 1e-5f);
  xn[t] = d0 * rstd * g[t] + be[t];
  xn[t + 256] = d1 * rstd * g[t + 256] + be[t + 256];
  __syncthreads();
  if (t < 160) {
    int j = t / 8, sg = t % 8;
    const float* wr = Wo + (size_t)j * DM + sg * 64;
    const float* xs = xn + sg * 64;
    float s = 0.f;
    #pragma unroll
    for (int k = 0; k < 64; ++k) s = fmaf(xs[k], wr[k], s);
    hp[j][sg] = s;
  }
  __syncthreads();
  if (t < 20) {
    float s = bo[t];
    #pragma unroll
    for (int k = 0; k < 8; ++k) s += hp[t][k];
    out[b * 20 + t] = s;
  }
}

extern "C" void kernel_launch(void* const* d_in, const int* in_sizes, int n_in,
                              void* d_out, int out_size, void* d_ws, size_t ws_size,
                              hipStream_t stream) {
  (void)in_sizes; (void)n_in; (void)out_size;
  const float* seq    = (const float*)d_in[0];
  const float* Wi     = (const float*)d_in[1];
  const float* bi     = (const float*)d_in[2];
  const float* Wo     = (const float*)d_in[3];
  const float* bo     = (const float*)d_in[4];
  const float* ln_g   = (const float*)d_in[5];
  const float* ln_b   = (const float*)d_in[6];
  const float* lWin   = (const float*)d_in[7];
  const float* lconvw = (const float*)d_in[8];
  const float* lconvb = (const float*)d_in[9];
  const float* lWx    = (const float*)d_in[10];
  const float* lWdt   = (const float*)d_in[11];
  const float* lbdt   = (const float*)d_in[12];
  const float* lAlog  = (const float*)d_in[13];
  const float* lD     = (const float*)d_in[14];
  const float* lWout  = (const float*)d_in[15];

  float* ws  = (float*)d_ws;
  float* X   = ws;                 // [4096][512]   = 2,097,152 floats
  float* XZ  = X + 2097152;        // [4096][2048]  = 8,388,608
  float* XB  = XZ + 8388608;       // [4096][1024]  = 4,194,304
  float* DBC = XB + 4194304;       // [4096][64]    = 262,144
  float* DEL = DBC + 262144;       // [4096][1024]  = 4,194,304 (delta, then y in-place)
  float* PQ  = DEL + 4194304;      // [NC*4096][32] floats; PART aliases (disjoint phase)
  float* PART = PQ;                // [8][4096][64] = 2M floats (xproj phase)

  // NC=64 needs 110,100,480 B (proven available: ws = 256 MiB observed r11).
  const bool nc64 = ws_size >= (size_t)110100480;

  k_init_x<<<dim3(Bx * Lx * DM / 256), 256, 0, stream>>>(seq, Wi, bi, X);

  for (int i = 0; i < NL; ++i) {
    const float* Win  = lWin   + (size_t)i * 2048 * 512;
    const float* cw   = lconvw + (size_t)i * EDx * 4;
    const float* cb   = lconvb + (size_t)i * EDx;
    const float* Wx   = lWx    + (size_t)i * 64 * EDx;
    const float* Wdt  = lWdt   + (size_t)i * EDx * DTR;
    const float* bdt  = lbdt   + (size_t)i * EDx;
    const float* Alog = lAlog  + (size_t)i * EDx * DS;
    const float* Dp   = lD     + (size_t)i * EDx;
    const float* Wout = lWout  + (size_t)i * DM * EDx;

    // xz = x @ Win^T            [4096,2048] K=512   (bf16x3 MFMA, in-kernel split)
    k_gemm_mfma<128, 128><<<dim3(32, 16), 256, 0, stream>>>(X, DM, Win, DM, XZ, 2 * EDx, DM);
    // xb = silu(causal_dwconv(xz[:, :ED]) + cb)
    k_conv_silu4<<<dim3(Bx * Lx * EDx / 1024), 256, 0, stream>>>(XZ, cw, cb, XB);
    // dbc = xb @ Wx^T  (split-K MFMA + reduce)
    k_xproj_mfma<8><<<dim3(32, 1, 8), 256, 0, stream>>>(XB, Wx, PART);
    k_redux<8><<<dim3(256), 256, 0, stream>>>(PART, DBC);
    // delta = softplus(dbc[:, :32] @ Wdt^T + bdt)
    k_gemm_tn<128, 64, 1><<<dim3(32, 16), 256, 0, stream>>>(DBC, 64, Wdt, DTR, bdt, DEL, EDx, DTR);
    // chunked selective scan + gating, 2 lanes/chain, y written over DEL
    if (nc64) {
      k_scan1<64><<<dim3(64 * 32), 256, 0, stream>>>(DEL, XB, DBC, Alog, PQ);
      k_scan2<64><<<dim3(4096 * DS / 256), 256, 0, stream>>>(PQ);
      k_scan3<64><<<dim3(64 * 32), 256, 0, stream>>>(DEL, XB, DBC, XZ, Alog, Dp, PQ);
    } else {
      k_scan1<32><<<dim3(32 * 32), 256, 0, stream>>>(DEL, XB, DBC, Alog, PQ);
      k_scan2<32><<<dim3(4096 * DS / 256), 256, 0, stream>>>(PQ);
      k_scan3<32><<<dim3(32 * 32), 256, 0, stream>>>(DEL, XB, DBC, XZ, Alog, Dp, PQ);
    }
    // x = y @ Wout^T            [4096,512] K=1024   (bf16x3 MFMA)
    k_gemm_mfma<128, 64><<<dim3(32, 8), 256, 0, stream>>>(DEL, EDx, Wout, EDx, X, DM, EDx);
  }

  k_ln_head<<<dim3(Bx), 256, 0, stream>>>(X, ln_g, ln_b, Wo, bo, (float*)d_out);
}